// Round 13
// baseline (199.914 us; speedup 1.0000x reference)
//
#include <hip/hip_runtime.h>

constexpr int NFEAT  = 256;
constexpr int NHID   = 128;
constexpr int NCLASS = 64;

typedef __attribute__((ext_vector_type(8))) short short8;   // 8 bf16 (4 VGPRs)
typedef __attribute__((ext_vector_type(4))) float floatx4;  // MFMA accumulator

__device__ __forceinline__ unsigned short f2bf(float x) {
    unsigned u = __float_as_uint(x);
    u += 0x7FFFu + ((u >> 16) & 1u);   // RNE
    return (unsigned short)(u >> 16);
}
__device__ __forceinline__ float bf_lo(unsigned int p) { return __uint_as_float(p << 16); }
__device__ __forceinline__ float bf_hi(unsigned int p) { return __uint_as_float(p & 0xFFFF0000u); }

constexpr int EPB = 8192;   // edges per scatter block
constexpr int CAP = 8192;   // fixed bucket capacity (mean ~4092 per bucket)

// ---------------- K1: scatter (bid<sgrid) | cast-x f32->bf16 | cast-W ----------------
// All independent; scatter's latency phases hide under cast-x's BW stream.
// bcur holds RELATIVE counts (pre-zeroed by memsetAsync); pos = (b<<13)+base+idx.
__global__ __launch_bounds__(256) void prep_fused_kernel(
    const float* __restrict__ x,
    const float* __restrict__ W1, const float* __restrict__ W2,
    unsigned short* __restrict__ xbf,
    unsigned short* __restrict__ W1T, unsigned short* __restrict__ W2T,
    const float* __restrict__ vals, const int* __restrict__ src,
    const int* __restrict__ dst, int* __restrict__ bcur,
    int2* __restrict__ tmp, int E, int M, int sgrid, int cxgrid)
{
    __shared__ int smem[1024];
    const int bid = blockIdx.x, tid = threadIdx.x;
    if (bid < sgrid) {
        int* cnt  = smem;
        int* base = smem + 512;
        for (int i = tid; i < 512; i += 256) cnt[i] = 0;
        __syncthreads();
        int begin = bid * EPB;
        int endi = begin + EPB; if (endi > E) endi = E;
        for (int i = begin + tid; i < endi; i += 256)
            atomicAdd(&cnt[dst[i] >> 8], 1);
        __syncthreads();
        for (int b = tid; b < 512; b += 256) {
            int c = cnt[b];
            base[b] = c ? atomicAdd(&bcur[b], c) : 0;
            cnt[b] = 0;
        }
        __syncthreads();
        for (int i = begin + tid; i < endi; i += 256) {
            int d = dst[i];
            int b = d >> 8;
            int pos = (b << 13) + base[b] + atomicAdd(&cnt[b], 1);
            tmp[pos] = make_int2(src[i] | ((d & 255) << 17), __float_as_int(vals[i]));
        }
    } else if (bid < sgrid + cxgrid) {
        // cast-x: block handles 4096 f32 -> 512 uint4 (8 bf16 each)
        const int blk = bid - sgrid;
        const float4* in4 = reinterpret_cast<const float4*>(x);
        uint4* o4 = reinterpret_cast<uint4*>(xbf);
        const long total8 = (long)M * NFEAT / 8;
        #pragma unroll
        for (int i = 0; i < 2; ++i) {
            long oidx = (long)blk * 512 + i * 256 + tid;
            if (oidx < total8) {
                float4 a = in4[oidx * 2], b = in4[oidx * 2 + 1];
                uint4 u;
                u.x = (unsigned)f2bf(a.x) | ((unsigned)f2bf(a.y) << 16);
                u.y = (unsigned)f2bf(a.z) | ((unsigned)f2bf(a.w) << 16);
                u.z = (unsigned)f2bf(b.x) | ((unsigned)f2bf(b.y) << 16);
                u.w = (unsigned)f2bf(b.z) | ((unsigned)f2bf(b.w) << 16);
                o4[oidx] = u;
            }
        }
    } else {
        int i = (bid - sgrid - cxgrid) * 256 + tid;
        if (i < NFEAT * NHID) {         // 256x128
            int k = i >> 7, n = i & 127;
            W1T[n * NFEAT + k] = f2bf(W1[i]);
        }
        if (i < NHID * NCLASS) {        // 128x64
            int k = i >> 6, n = i & 63;
            W2T[n * NHID + k] = f2bf(W2[i]);
        }
    }
}

// ---------------- fine body (shared by fused + standalone) ----------------
__device__ __forceinline__ void fine_body(
    int b, int tid, int* cnt, int* excl, int* cur,
    const int* __restrict__ bcur, const int2* __restrict__ tmp,
    int* __restrict__ row_beg, int* __restrict__ row_end,
    int2* __restrict__ pairs, int M)
{
    const int beg = b * CAP;
    int c0 = bcur[b]; if (c0 > CAP) c0 = CAP;
    const int endi = beg + c0;
    cnt[tid] = 0;
    __syncthreads();
    for (int j = beg + tid; j < endi; j += 256)
        atomicAdd(&cnt[(tmp[j].x >> 17) & 255], 1);
    __syncthreads();
    int v = cnt[tid];
    excl[tid] = v;
    __syncthreads();
    for (int off = 1; off < 256; off <<= 1) {
        int u = (tid >= off) ? excl[tid - off] : 0;
        __syncthreads();
        excl[tid] += u;
        __syncthreads();
    }
    int ex = excl[tid] - v;
    excl[tid] = ex;
    cur[tid] = 0;
    int row = (b << 8) + tid;
    if (row < M) { row_beg[row] = beg + ex; row_end[row] = beg + ex + v; }
    __syncthreads();
    for (int j = beg + tid; j < endi; j += 256) {
        int2 p = tmp[j];
        int dl = (p.x >> 17) & 255;
        int pos = beg + excl[dl] + atomicAdd(&cur[dl], 1);
        pairs[pos] = p;
    }
}

// ---------------- K2: fine (bid<fgrid) + GEMM1 bf16-A (round-5 proven structure) ----
__global__ __launch_bounds__(256) void gemm1_fine_fused_kernel(
    const unsigned short* __restrict__ A,      // xbf [M][256] bf16
    const unsigned short* __restrict__ BT,     // W1T [128][256] bf16
    unsigned short* __restrict__ C,            // sup [M][128] bf16
    int M,
    const int* __restrict__ bcur, const int2* __restrict__ tmp,
    int* __restrict__ row_beg, int* __restrict__ row_end,
    int2* __restrict__ pairs, int fgrid)
{
    constexpr int KTOT = NFEAT, BN = NHID;
    constexpr int NB  = BN / 16;
    constexpr int LDA = 72;
    __shared__ unsigned short smem[64 * LDA + BN * LDA];   // 27648 B

    const int tid = threadIdx.x;
    if ((int)blockIdx.x < fgrid) {
        int* cnt  = reinterpret_cast<int*>(smem);
        fine_body(blockIdx.x, tid, cnt, cnt + 256, cnt + 512,
                  bcur, tmp, row_beg, row_end, pairs, M);
        return;
    }

    unsigned short* As = smem;
    unsigned short* Bs = smem + 64 * LDA;
    const int w = tid >> 6, l = tid & 63;
    const int row0 = ((int)blockIdx.x - fgrid) * 64;

    floatx4 acc[NB];
    #pragma unroll
    for (int i = 0; i < NB; ++i) acc[i] = (floatx4){0.f, 0.f, 0.f, 0.f};

    for (int k0 = 0; k0 < KTOT; k0 += 64) {
        #pragma unroll
        for (int i = 0; i < 2; ++i) {                       // A: 2 uint4/thread
            int c = tid + 256 * i;
            int r = c >> 3, k8 = (c & 7) * 8;
            int row = row0 + r;
            uint4 v = (row < M) ? *reinterpret_cast<const uint4*>(A + (size_t)row * KTOT + k0 + k8)
                                : make_uint4(0u, 0u, 0u, 0u);
            *reinterpret_cast<uint4*>(&As[r * LDA + k8]) = v;
        }
        #pragma unroll
        for (int i = 0; i < BN * 8 / 256; ++i) {            // B: 4 uint4/thread
            int c = tid + 256 * i;
            int n = c >> 3, k8 = (c & 7) * 8;
            uint4 v = *reinterpret_cast<const uint4*>(BT + (size_t)n * KTOT + k0 + k8);
            *reinterpret_cast<uint4*>(&Bs[n * LDA + k8]) = v;
        }
        __syncthreads();
        #pragma unroll
        for (int ks = 0; ks < 2; ++ks) {
            short8 a = *reinterpret_cast<const short8*>(&As[(16 * w + (l & 15)) * LDA + ks * 32 + (l >> 4) * 8]);
            #pragma unroll
            for (int nb = 0; nb < NB; ++nb) {
                short8 b = *reinterpret_cast<const short8*>(&Bs[(16 * nb + (l & 15)) * LDA + ks * 32 + (l >> 4) * 8]);
                acc[nb] = __builtin_amdgcn_mfma_f32_16x16x32_bf16(a, b, acc[nb], 0, 0, 0);
            }
        }
        __syncthreads();
    }
    const int cr = (l >> 4) * 4;
    const int cc = l & 15;
    #pragma unroll
    for (int nb = 0; nb < NB; ++nb) {
        #pragma unroll
        for (int r = 0; r < 4; ++r) {
            int row = row0 + 16 * w + cr + r;
            if (row < M) C[(size_t)row * BN + 16 * nb + cc] = f2bf(acc[nb][r]);
        }
    }
}

// standalone fine (small-workspace fallback: pairs aliases xbf, so run after K2)
__global__ __launch_bounds__(256) void bucket_fine_kernel(
    const int* __restrict__ bcur, const int2* __restrict__ tmp,
    int* __restrict__ row_beg, int* __restrict__ row_end,
    int2* __restrict__ pairs, int M)
{
    __shared__ int smem[768];
    fine_body(blockIdx.x, threadIdx.x, smem, smem + 256, smem + 512,
              bcur, tmp, row_beg, row_end, pairs, M);
}

// ---------------- K4: FUSED layer-1 gather + relu + GEMM2 (unchanged) ----------------
__global__ __launch_bounds__(256) void spmm_gemm2_fused_kernel(
    const int*  __restrict__ row_beg,
    const int*  __restrict__ row_end,
    const int2* __restrict__ pairs,
    const unsigned short* __restrict__ dense,   // sup_bf  [M][128]
    const unsigned short* __restrict__ W2T,     // [64][128] bf16 (L1-resident)
    unsigned short*       __restrict__ sup2,    // [M][64] bf16
    int M)
{
    __shared__ unsigned short hs[16 * 128];     // 4KB, swizzled: byte ^= (r&7)<<4
    const int wv = threadIdx.x >> 6, l = threadIdx.x & 63;
    const int g = l >> 4, t = l & 15;
    const int row = blockIdx.x * 16 + wv * 4 + g;
    int beg = 0, end = 0;
    if (row < M) { beg = row_beg[row]; end = row_end[row]; }
    const uint4* d4 = reinterpret_cast<const uint4*>(dense);
    float2 a0 = {0.f, 0.f}, a1 = {0.f, 0.f}, a2 = {0.f, 0.f}, a3 = {0.f, 0.f};
    int j = beg;
    for (; j + 4 <= end; j += 4) {
        int2 p0 = pairs[j], p1 = pairs[j + 1], p2 = pairs[j + 2], p3 = pairs[j + 3];
        uint4 x0 = d4[(size_t)(p0.x & 0x1FFFF) * 16 + t];
        uint4 x1 = d4[(size_t)(p1.x & 0x1FFFF) * 16 + t];
        uint4 x2 = d4[(size_t)(p2.x & 0x1FFFF) * 16 + t];
        uint4 x3 = d4[(size_t)(p3.x & 0x1FFFF) * 16 + t];
        float v0 = __int_as_float(p0.y), v1 = __int_as_float(p1.y);
        float v2 = __int_as_float(p2.y), v3 = __int_as_float(p3.y);
        a0.x += v0 * bf_lo(x0.x); a0.y += v0 * bf_hi(x0.x);
        a1.x += v0 * bf_lo(x0.y); a1.y += v0 * bf_hi(x0.y);
        a2.x += v0 * bf_lo(x0.z); a2.y += v0 * bf_hi(x0.z);
        a3.x += v0 * bf_lo(x0.w); a3.y += v0 * bf_hi(x0.w);
        a0.x += v1 * bf_lo(x1.x); a0.y += v1 * bf_hi(x1.x);
        a1.x += v1 * bf_lo(x1.y); a1.y += v1 * bf_hi(x1.y);
        a2.x += v1 * bf_lo(x1.z); a2.y += v1 * bf_hi(x1.z);
        a3.x += v1 * bf_lo(x1.w); a3.y += v1 * bf_hi(x1.w);
        a0.x += v2 * bf_lo(x2.x); a0.y += v2 * bf_hi(x2.x);
        a1.x += v2 * bf_lo(x2.y); a1.y += v2 * bf_hi(x2.y);
        a2.x += v2 * bf_lo(x2.z); a2.y += v2 * bf_hi(x2.z);
        a3.x += v2 * bf_lo(x2.w); a3.y += v2 * bf_hi(x2.w);
        a0.x += v3 * bf_lo(x3.x); a0.y += v3 * bf_hi(x3.x);
        a1.x += v3 * bf_lo(x3.y); a1.y += v3 * bf_hi(x3.y);
        a2.x += v3 * bf_lo(x3.z); a2.y += v3 * bf_hi(x3.z);
        a3.x += v3 * bf_lo(x3.w); a3.y += v3 * bf_hi(x3.w);
    }
    for (; j < end; ++j) {
        int2 p = pairs[j];
        uint4 x = d4[(size_t)(p.x & 0x1FFFF) * 16 + t];
        float v = __int_as_float(p.y);
        a0.x += v * bf_lo(x.x); a0.y += v * bf_hi(x.x);
        a1.x += v * bf_lo(x.y); a1.y += v * bf_hi(x.y);
        a2.x += v * bf_lo(x.z); a2.y += v * bf_hi(x.z);
        a3.x += v * bf_lo(x.w); a3.y += v * bf_hi(x.w);
    }
    {
        uint4 o;
        o.x = (unsigned)f2bf(fmaxf(a0.x, 0.f)) | ((unsigned)f2bf(fmaxf(a0.y, 0.f)) << 16);
        o.y = (unsigned)f2bf(fmaxf(a1.x, 0.f)) | ((unsigned)f2bf(fmaxf(a1.y, 0.f)) << 16);
        o.z = (unsigned)f2bf(fmaxf(a2.x, 0.f)) | ((unsigned)f2bf(fmaxf(a2.y, 0.f)) << 16);
        o.w = (unsigned)f2bf(fmaxf(a3.x, 0.f)) | ((unsigned)f2bf(fmaxf(a3.y, 0.f)) << 16);
        const int rloc = wv * 4 + g;
        const int byte = (t * 16) ^ ((rloc & 7) << 4);
        *reinterpret_cast<uint4*>(reinterpret_cast<char*>(hs) + rloc * 256 + byte) = o;
    }
    __syncthreads();
    floatx4 acc = (floatx4){0.f, 0.f, 0.f, 0.f};
    const int lr = l & 15, lk = l >> 4;
    #pragma unroll
    for (int ks = 0; ks < 4; ++ks) {
        const int byte = (ks * 64 + lk * 16) ^ ((lr & 7) << 4);
        short8 a = *reinterpret_cast<const short8*>(reinterpret_cast<const char*>(hs) + lr * 256 + byte);
        short8 b = *reinterpret_cast<const short8*>(W2T + (size_t)(wv * 16 + lr) * NHID + ks * 32 + lk * 8);
        acc = __builtin_amdgcn_mfma_f32_16x16x32_bf16(a, b, acc, 0, 0, 0);
    }
    const int cr = lk * 4, cc = lr;
    #pragma unroll
    for (int q = 0; q < 4; ++q) {
        int orow = blockIdx.x * 16 + cr + q;
        if (orow < M) sup2[(size_t)orow * NCLASS + wv * 16 + cc] = f2bf(acc[q]);
    }
}

// ---------------- K5: layer-2 gather (unchanged) ----------------
__global__ __launch_bounds__(256) void spmm_gather64_kernel(
    const int*  __restrict__ row_beg,
    const int*  __restrict__ row_end,
    const int2* __restrict__ pairs,
    const unsigned short* __restrict__ dense,   // bf16 [M][64]
    float*                __restrict__ out,     // f32 [M][64]
    int M)
{
    const int wv = threadIdx.x >> 6, l = threadIdx.x & 63;
    const int g = l >> 3, t = l & 7;
    const int row = blockIdx.x * 32 + wv * 8 + g;
    int beg = 0, end = 0;
    if (row < M) { beg = row_beg[row]; end = row_end[row]; }
    const uint4* d4 = reinterpret_cast<const uint4*>(dense);
    float2 a0 = {0.f, 0.f}, a1 = {0.f, 0.f}, a2 = {0.f, 0.f}, a3 = {0.f, 0.f};
    int j = beg;
    for (; j + 4 <= end; j += 4) {
        int2 p0 = pairs[j], p1 = pairs[j + 1], p2 = pairs[j + 2], p3 = pairs[j + 3];
        uint4 x0 = d4[(size_t)(p0.x & 0x1FFFF) * 8 + t];
        uint4 x1 = d4[(size_t)(p1.x & 0x1FFFF) * 8 + t];
        uint4 x2 = d4[(size_t)(p2.x & 0x1FFFF) * 8 + t];
        uint4 x3 = d4[(size_t)(p3.x & 0x1FFFF) * 8 + t];
        float v0 = __int_as_float(p0.y), v1 = __int_as_float(p1.y);
        float v2 = __int_as_float(p2.y), v3 = __int_as_float(p3.y);
        a0.x += v0 * bf_lo(x0.x); a0.y += v0 * bf_hi(x0.x);
        a1.x += v0 * bf_lo(x0.y); a1.y += v0 * bf_hi(x0.y);
        a2.x += v0 * bf_lo(x0.z); a2.y += v0 * bf_hi(x0.z);
        a3.x += v0 * bf_lo(x0.w); a3.y += v0 * bf_hi(x0.w);
        a0.x += v1 * bf_lo(x1.x); a0.y += v1 * bf_hi(x1.x);
        a1.x += v1 * bf_lo(x1.y); a1.y += v1 * bf_hi(x1.y);
        a2.x += v1 * bf_lo(x1.z); a2.y += v1 * bf_hi(x1.z);
        a3.x += v1 * bf_lo(x1.w); a3.y += v1 * bf_hi(x1.w);
        a0.x += v2 * bf_lo(x2.x); a0.y += v2 * bf_hi(x2.x);
        a1.x += v2 * bf_lo(x2.y); a1.y += v2 * bf_hi(x2.y);
        a2.x += v2 * bf_lo(x2.z); a2.y += v2 * bf_hi(x2.z);
        a3.x += v2 * bf_lo(x2.w); a3.y += v2 * bf_hi(x2.w);
        a0.x += v3 * bf_lo(x3.x); a0.y += v3 * bf_hi(x3.x);
        a1.x += v3 * bf_lo(x3.y); a1.y += v3 * bf_hi(x3.y);
        a2.x += v3 * bf_lo(x3.z); a2.y += v3 * bf_hi(x3.z);
        a3.x += v3 * bf_lo(x3.w); a3.y += v3 * bf_hi(x3.w);
    }
    for (; j < end; ++j) {
        int2 p = pairs[j];
        uint4 x = d4[(size_t)(p.x & 0x1FFFF) * 8 + t];
        float v = __int_as_float(p.y);
        a0.x += v * bf_lo(x.x); a0.y += v * bf_hi(x.x);
        a1.x += v * bf_lo(x.y); a1.y += v * bf_hi(x.y);
        a2.x += v * bf_lo(x.z); a2.y += v * bf_hi(x.z);
        a3.x += v * bf_lo(x.w); a3.y += v * bf_hi(x.w);
    }
    if (row < M) {
        float4 o0 = make_float4(a0.x, a0.y, a1.x, a1.y);
        float4 o1 = make_float4(a2.x, a2.y, a3.x, a3.y);
        float4* op = reinterpret_cast<float4*>(out + (size_t)row * 64 + t * 8);
        op[0] = o0;
        op[1] = o1;
    }
}

extern "C" void kernel_launch(void* const* d_in, const int* in_sizes, int n_in,
                              void* d_out, int out_size, void* d_ws, size_t ws_size,
                              hipStream_t stream) {
    const float* x  = (const float*)d_in[0];
    const float* W1 = (const float*)d_in[1];
    const float* W2 = (const float*)d_in[2];
    const float* ev = (const float*)d_in[3];
    const int*   es = (const int*)d_in[4];
    const int*   ed = (const int*)d_in[5];
    float* out = (float*)d_out;

    const int M = in_sizes[0] / NFEAT;   // 100000
    const int E = in_sizes[3];           // 1.6M
    const int nbuk = (M + 255) >> 8;     // 391

    size_t off = 0;
    auto alloc = [&](size_t bytes) -> void* {
        void* p = (char*)d_ws + off;
        off += (bytes + 255) & ~(size_t)255;
        return p;
    };
    unsigned short* xbf     = (unsigned short*)alloc((size_t)M * NFEAT * 2);   // 51.2MB
    unsigned short* sup_bf  = (unsigned short*)alloc((size_t)M * NHID * 2);
    unsigned short* sup2_bf = (unsigned short*)alloc((size_t)M * NCLASS * 2);
    unsigned short* W1T     = (unsigned short*)alloc((size_t)NHID * NFEAT * 2);
    unsigned short* W2T     = (unsigned short*)alloc((size_t)NCLASS * NHID * 2);
    int*  row_beg = (int*) alloc((size_t)M * sizeof(int));
    int*  row_end = (int*) alloc((size_t)M * sizeof(int));
    int*  bcur    = (int*) alloc(512 * sizeof(int));
    int2* tmp     = (int2*)alloc((size_t)nbuk * CAP * sizeof(int2));           // gapped

    const size_t pairs_bytes = (size_t)nbuk * CAP * sizeof(int2);
    const bool big_ws = (off + pairs_bytes + 256 <= ws_size);
    int2* pairs = big_ws ? (int2*)alloc(pairs_bytes) : (int2*)xbf;  // small path: reuse xbf after K2

    const int sgrid  = (E + EPB - 1) / EPB;                 // 196
    const int cxgrid = (M * NFEAT + 4095) / 4096;           // 6250
    const int cwgrid = (NFEAT * NHID + 255) / 256;          // 128
    const int fgrid  = nbuk;                                // 391
    const int g1grid = (M + 63) / 64;                       // 1563

    // K0: zero relative bucket cursors
    hipMemsetAsync(bcur, 0, 512 * sizeof(int), stream);

    // K1: scatter || cast-x || cast-W
    prep_fused_kernel<<<sgrid + cxgrid + cwgrid, 256, 0, stream>>>(
        x, W1, W2, xbf, W1T, W2T, ev, es, ed, bcur, tmp, E, M, sgrid, cxgrid);

    if (big_ws) {
        // K2: fine || gemm1-bf16
        gemm1_fine_fused_kernel<<<fgrid + g1grid, 256, 0, stream>>>(
            xbf, W1T, sup_bf, M, bcur, tmp, row_beg, row_end, pairs, fgrid);
    } else {
        // K2: gemm1-bf16 alone; K3: fine (pairs aliases xbf, safe after K2)
        gemm1_fine_fused_kernel<<<g1grid, 256, 0, stream>>>(
            xbf, W1T, sup_bf, M, bcur, tmp, row_beg, row_end, pairs, 0);
        bucket_fine_kernel<<<nbuk, 256, 0, stream>>>(bcur, tmp, row_beg, row_end, pairs, M);
    }

    // K4: sup2 = relu(spmm(A, sup)) @ W2
    spmm_gemm2_fused_kernel<<<(M + 15) / 16, 256, 0, stream>>>(
        row_beg, row_end, pairs, sup_bf, W2T, sup2_bf, M);

    // K5: layer-2 aggregate -> f32 out
    spmm_gather64_kernel<<<(M + 31) / 32, 256, 0, stream>>>(
        row_beg, row_end, pairs, sup2_bf, out, M);
}

// Round 14
// 165.332 us; speedup vs baseline: 1.2092x; 1.2092x over previous
//
#include <hip/hip_runtime.h>

constexpr int NFEAT  = 256;
constexpr int NHID   = 128;
constexpr int NCLASS = 64;

typedef __attribute__((ext_vector_type(8))) short short8;   // 8 bf16 (4 VGPRs)
typedef __attribute__((ext_vector_type(4))) float floatx4;  // MFMA accumulator

__device__ __forceinline__ unsigned short f2bf(float x) {
    unsigned u = __float_as_uint(x);
    u += 0x7FFFu + ((u >> 16) & 1u);   // RNE
    return (unsigned short)(u >> 16);
}
__device__ __forceinline__ float bf_lo(unsigned int p) { return __uint_as_float(p << 16); }
__device__ __forceinline__ float bf_hi(unsigned int p) { return __uint_as_float(p & 0xFFFF0000u); }

// async global->LDS, 16B per lane; LDS dest = uniform base + lane*16 (HW)
__device__ __forceinline__ void gload16(const void* g, void* l) {
    __builtin_amdgcn_global_load_lds(
        (const __attribute__((address_space(1))) void*)g,
        (__attribute__((address_space(3))) void*)l, 16, 0, 0);
}

constexpr int EPB = 8192;   // edges per scatter block
constexpr int CAP = 8192;   // fixed bucket capacity (mean ~4092 per bucket)

// ---------------- K1: W cast + bcur init (block 0) ----------------
__global__ __launch_bounds__(256) void init_cast_kernel(
    const float* __restrict__ W1, const float* __restrict__ W2,
    unsigned short* __restrict__ W1T, unsigned short* __restrict__ W2T,
    int* __restrict__ bcur, int nbuk)
{
    if (blockIdx.x == 0) {
        for (int b = threadIdx.x; b < nbuk; b += 256) bcur[b] = b * CAP;
        return;
    }
    int i = ((int)blockIdx.x - 1) * 256 + threadIdx.x;
    if (i < NFEAT * NHID) {         // 256x128
        int k = i >> 7, n = i & 127;
        W1T[n * NFEAT + k] = f2bf(W1[i]);
    }
    if (i < NHID * NCLASS) {        // 128x64
        int k = i >> 6, n = i & 63;
        W2T[n * NHID + k] = f2bf(W2[i]);
    }
}

// ---------------- K2: bucket_scatter (blocks < sgrid) + GEMM1 (rest) ----------------
// GEMM1: A direct global->reg (rows are wave-private, no reuse -> no LDS);
// B staged via global_load_lds, double-buffered, XOR-swizzled source (rule #21),
// T3 2-phase prefetch: issue next B-tile before MFMA, one barrier per K-tile.
__global__ __launch_bounds__(256) void gemm1_scatter_fused_kernel(
    const float* __restrict__ A,               // x [M][256] f32
    const unsigned short* __restrict__ BT,     // W1T [128][256] bf16
    unsigned short* __restrict__ C,            // sup [M][128] bf16
    int M,
    const float* __restrict__ vals, const int* __restrict__ src,
    const int* __restrict__ dst, int* __restrict__ bcur,
    int2* __restrict__ tmp, int E, int sgrid)
{
    constexpr int KTOT = NFEAT, BN = NHID;
    __shared__ unsigned short smem[2 * BN * 64];   // 32768 B: B double buffer

    const int tid = threadIdx.x;
    if ((int)blockIdx.x < sgrid) {
        // ---- scatter body (bump allocation, absolute cursors) ----
        int* cnt  = reinterpret_cast<int*>(smem);
        int* base = cnt + 512;
        for (int i = tid; i < 512; i += 256) cnt[i] = 0;
        __syncthreads();
        int begin = blockIdx.x * EPB;
        int endi = begin + EPB; if (endi > E) endi = E;
        for (int i = begin + tid; i < endi; i += 256)
            atomicAdd(&cnt[dst[i] >> 8], 1);
        __syncthreads();
        for (int b = tid; b < 512; b += 256) {
            int c = cnt[b];
            base[b] = c ? atomicAdd(&bcur[b], c) : 0;
            cnt[b] = 0;
        }
        __syncthreads();
        for (int i = begin + tid; i < endi; i += 256) {
            int d = dst[i];
            int b = d >> 8;
            int pos = base[b] + atomicAdd(&cnt[b], 1);
            tmp[pos] = make_int2(src[i] | ((d & 255) << 17), __float_as_int(vals[i]));
        }
        return;
    }

    // ---- GEMM1 body ----
    const int w = tid >> 6, l = tid & 63;
    const int lr = l & 15, lk = l >> 4;
    const int row0 = ((int)blockIdx.x - sgrid) * 64;
    const int ra = row0 + 16 * w + lr;
    const float* Arow = A + (size_t)((ra < M) ? ra : (M - 1)) * KTOT;

    // B stage: 16 instructions of 1KB per tile, 4 per wave.
    // inst i covers rows 8i..8i+7; lane l -> row 8i+(l>>3), LDS slot l&7,
    // global chunk (l&7)^(l>>3)  (inverse-swizzled source, linear LDS dest).
    const char* BTb = (const char*)BT;
    char* Bb = (char*)smem;
    auto stageB = [&](int buf, int kt) {
        #pragma unroll
        for (int j = 0; j < 4; ++j) {
            int i = w * 4 + j;
            int r = i * 8 + (l >> 3);
            int chunk = (l & 7) ^ (l >> 3);
            gload16(BTb + (size_t)r * (KTOT * 2) + kt * 128 + chunk * 16,
                    Bb + buf * 16384 + i * 1024);
        }
    };

    floatx4 acc[8];
    #pragma unroll
    for (int i = 0; i < 8; ++i) acc[i] = (floatx4){0.f, 0.f, 0.f, 0.f};

    stageB(0, 0);
    __syncthreads();
    int cur = 0;
    for (int kt = 0; kt < 4; ++kt) {
        if (kt < 3) stageB(cur ^ 1, kt + 1);   // prefetch rides under MFMA
        #pragma unroll
        for (int ks = 0; ks < 2; ++ks) {
            const float* ap = Arow + kt * 64 + ks * 32 + lk * 8;
            float4 v0 = *reinterpret_cast<const float4*>(ap);
            float4 v1 = *reinterpret_cast<const float4*>(ap + 4);
            short8 a;
            a[0] = (short)f2bf(v0.x); a[1] = (short)f2bf(v0.y);
            a[2] = (short)f2bf(v0.z); a[3] = (short)f2bf(v0.w);
            a[4] = (short)f2bf(v1.x); a[5] = (short)f2bf(v1.y);
            a[6] = (short)f2bf(v1.z); a[7] = (short)f2bf(v1.w);
            #pragma unroll
            for (int nb = 0; nb < 8; ++nb) {
                int rb = nb * 16 + lr;
                int byteo = cur * 16384 + rb * 128 + (((ks * 4 + lk) ^ (lr & 7)) << 4);
                short8 b = *reinterpret_cast<const short8*>(Bb + byteo);
                acc[nb] = __builtin_amdgcn_mfma_f32_16x16x32_bf16(a, b, acc[nb], 0, 0, 0);
            }
        }
        __syncthreads();   // drains prefetch vmcnt + protects buffer swap
        cur ^= 1;
    }
    const int cr = lk * 4, cc = lr;
    #pragma unroll
    for (int nb = 0; nb < 8; ++nb) {
        #pragma unroll
        for (int r = 0; r < 4; ++r) {
            int row = row0 + 16 * w + cr + r;
            if (row < M) C[(size_t)row * BN + 16 * nb + cc] = f2bf(acc[nb][r]);
        }
    }
}

// ---------------- K3: per-row CSR within buckets (gapped layout) ----------------
__global__ __launch_bounds__(256) void bucket_fine_kernel(
    const int* __restrict__ bcur,              // final cursors: end of bucket b
    const int2* __restrict__ tmp,
    int* __restrict__ row_beg, int* __restrict__ row_end,
    int2* __restrict__ pairs, int M)
{
    __shared__ int cnt[256];
    __shared__ int excl[256];
    __shared__ int cur[256];
    const int b = blockIdx.x;
    const int beg = b * CAP, endi = bcur[b];
    const int t = threadIdx.x;
    cnt[t] = 0;
    __syncthreads();
    for (int j = beg + t; j < endi; j += 256)
        atomicAdd(&cnt[(tmp[j].x >> 17) & 255], 1);
    __syncthreads();
    int v = cnt[t];
    excl[t] = v;
    __syncthreads();
    for (int off = 1; off < 256; off <<= 1) {
        int u = (t >= off) ? excl[t - off] : 0;
        __syncthreads();
        excl[t] += u;
        __syncthreads();
    }
    int ex = excl[t] - v;
    excl[t] = ex;
    cur[t] = 0;
    int row = (b << 8) + t;
    if (row < M) { row_beg[row] = beg + ex; row_end[row] = beg + ex + v; }
    __syncthreads();
    for (int j = beg + t; j < endi; j += 256) {
        int2 p = tmp[j];
        int dl = (p.x >> 17) & 255;
        int pos = beg + excl[dl] + atomicAdd(&cur[dl], 1);
        pairs[pos] = p;
    }
}

// ---------------- K4: FUSED layer-1 gather + relu + GEMM2 ----------------
__global__ __launch_bounds__(256) void spmm_gemm2_fused_kernel(
    const int*  __restrict__ row_beg,
    const int*  __restrict__ row_end,
    const int2* __restrict__ pairs,
    const unsigned short* __restrict__ dense,   // sup_bf  [M][128]
    const unsigned short* __restrict__ W2T,     // [64][128] bf16 (L1-resident)
    unsigned short*       __restrict__ sup2,    // [M][64] bf16
    int M)
{
    __shared__ unsigned short hs[16 * 128];     // 4KB, swizzled: byte ^= (r&7)<<4
    const int wv = threadIdx.x >> 6, l = threadIdx.x & 63;
    const int g = l >> 4, t = l & 15;
    const int row = blockIdx.x * 16 + wv * 4 + g;
    int beg = 0, end = 0;
    if (row < M) { beg = row_beg[row]; end = row_end[row]; }
    const uint4* d4 = reinterpret_cast<const uint4*>(dense);
    float2 a0 = {0.f, 0.f}, a1 = {0.f, 0.f}, a2 = {0.f, 0.f}, a3 = {0.f, 0.f};
    int j = beg;
    for (; j + 4 <= end; j += 4) {
        int2 p0 = pairs[j], p1 = pairs[j + 1], p2 = pairs[j + 2], p3 = pairs[j + 3];
        uint4 x0 = d4[(size_t)(p0.x & 0x1FFFF) * 16 + t];
        uint4 x1 = d4[(size_t)(p1.x & 0x1FFFF) * 16 + t];
        uint4 x2 = d4[(size_t)(p2.x & 0x1FFFF) * 16 + t];
        uint4 x3 = d4[(size_t)(p3.x & 0x1FFFF) * 16 + t];
        float v0 = __int_as_float(p0.y), v1 = __int_as_float(p1.y);
        float v2 = __int_as_float(p2.y), v3 = __int_as_float(p3.y);
        a0.x += v0 * bf_lo(x0.x); a0.y += v0 * bf_hi(x0.x);
        a1.x += v0 * bf_lo(x0.y); a1.y += v0 * bf_hi(x0.y);
        a2.x += v0 * bf_lo(x0.z); a2.y += v0 * bf_hi(x0.z);
        a3.x += v0 * bf_lo(x0.w); a3.y += v0 * bf_hi(x0.w);
        a0.x += v1 * bf_lo(x1.x); a0.y += v1 * bf_hi(x1.x);
        a1.x += v1 * bf_lo(x1.y); a1.y += v1 * bf_hi(x1.y);
        a2.x += v1 * bf_lo(x1.z); a2.y += v1 * bf_hi(x1.z);
        a3.x += v1 * bf_lo(x1.w); a3.y += v1 * bf_hi(x1.w);
        a0.x += v2 * bf_lo(x2.x); a0.y += v2 * bf_hi(x2.x);
        a1.x += v2 * bf_lo(x2.y); a1.y += v2 * bf_hi(x2.y);
        a2.x += v2 * bf_lo(x2.z); a2.y += v2 * bf_hi(x2.z);
        a3.x += v2 * bf_lo(x2.w); a3.y += v2 * bf_hi(x2.w);
        a0.x += v3 * bf_lo(x3.x); a0.y += v3 * bf_hi(x3.x);
        a1.x += v3 * bf_lo(x3.y); a1.y += v3 * bf_hi(x3.y);
        a2.x += v3 * bf_lo(x3.z); a2.y += v3 * bf_hi(x3.z);
        a3.x += v3 * bf_lo(x3.w); a3.y += v3 * bf_hi(x3.w);
    }
    for (; j < end; ++j) {
        int2 p = pairs[j];
        uint4 x = d4[(size_t)(p.x & 0x1FFFF) * 16 + t];
        float v = __int_as_float(p.y);
        a0.x += v * bf_lo(x.x); a0.y += v * bf_hi(x.x);
        a1.x += v * bf_lo(x.y); a1.y += v * bf_hi(x.y);
        a2.x += v * bf_lo(x.z); a2.y += v * bf_hi(x.z);
        a3.x += v * bf_lo(x.w); a3.y += v * bf_hi(x.w);
    }
    {
        uint4 o;
        o.x = (unsigned)f2bf(fmaxf(a0.x, 0.f)) | ((unsigned)f2bf(fmaxf(a0.y, 0.f)) << 16);
        o.y = (unsigned)f2bf(fmaxf(a1.x, 0.f)) | ((unsigned)f2bf(fmaxf(a1.y, 0.f)) << 16);
        o.z = (unsigned)f2bf(fmaxf(a2.x, 0.f)) | ((unsigned)f2bf(fmaxf(a2.y, 0.f)) << 16);
        o.w = (unsigned)f2bf(fmaxf(a3.x, 0.f)) | ((unsigned)f2bf(fmaxf(a3.y, 0.f)) << 16);
        const int rloc = wv * 4 + g;
        const int byte = (t * 16) ^ ((rloc & 7) << 4);
        *reinterpret_cast<uint4*>(reinterpret_cast<char*>(hs) + rloc * 256 + byte) = o;
    }
    __syncthreads();
    floatx4 acc = (floatx4){0.f, 0.f, 0.f, 0.f};
    const int lr = l & 15, lk = l >> 4;
    #pragma unroll
    for (int ks = 0; ks < 4; ++ks) {
        const int byte = (ks * 64 + lk * 16) ^ ((lr & 7) << 4);
        short8 a = *reinterpret_cast<const short8*>(reinterpret_cast<const char*>(hs) + lr * 256 + byte);
        short8 b = *reinterpret_cast<const short8*>(W2T + (size_t)(wv * 16 + lr) * NHID + ks * 32 + lk * 8);
        acc = __builtin_amdgcn_mfma_f32_16x16x32_bf16(a, b, acc, 0, 0, 0);
    }
    const int cr = lk * 4, cc = lr;
    #pragma unroll
    for (int q = 0; q < 4; ++q) {
        int orow = blockIdx.x * 16 + cr + q;
        if (orow < M) sup2[(size_t)orow * NCLASS + wv * 16 + cc] = f2bf(acc[q]);
    }
}

// ---------------- K5: layer-2 gather, D=64, 8-lane group per dst row, f32 out ----------------
__global__ __launch_bounds__(256) void spmm_gather64_kernel(
    const int*  __restrict__ row_beg,
    const int*  __restrict__ row_end,
    const int2* __restrict__ pairs,
    const unsigned short* __restrict__ dense,   // bf16 [M][64]
    float*                __restrict__ out,     // f32 [M][64]
    int M)
{
    const int wv = threadIdx.x >> 6, l = threadIdx.x & 63;
    const int g = l >> 3, t = l & 7;
    const int row = blockIdx.x * 32 + wv * 8 + g;
    int beg = 0, end = 0;
    if (row < M) { beg = row_beg[row]; end = row_end[row]; }
    const uint4* d4 = reinterpret_cast<const uint4*>(dense);
    float2 a0 = {0.f, 0.f}, a1 = {0.f, 0.f}, a2 = {0.f, 0.f}, a3 = {0.f, 0.f};
    int j = beg;
    for (; j + 4 <= end; j += 4) {
        int2 p0 = pairs[j], p1 = pairs[j + 1], p2 = pairs[j + 2], p3 = pairs[j + 3];
        uint4 x0 = d4[(size_t)(p0.x & 0x1FFFF) * 8 + t];
        uint4 x1 = d4[(size_t)(p1.x & 0x1FFFF) * 8 + t];
        uint4 x2 = d4[(size_t)(p2.x & 0x1FFFF) * 8 + t];
        uint4 x3 = d4[(size_t)(p3.x & 0x1FFFF) * 8 + t];
        float v0 = __int_as_float(p0.y), v1 = __int_as_float(p1.y);
        float v2 = __int_as_float(p2.y), v3 = __int_as_float(p3.y);
        a0.x += v0 * bf_lo(x0.x); a0.y += v0 * bf_hi(x0.x);
        a1.x += v0 * bf_lo(x0.y); a1.y += v0 * bf_hi(x0.y);
        a2.x += v0 * bf_lo(x0.z); a2.y += v0 * bf_hi(x0.z);
        a3.x += v0 * bf_lo(x0.w); a3.y += v0 * bf_hi(x0.w);
        a0.x += v1 * bf_lo(x1.x); a0.y += v1 * bf_hi(x1.x);
        a1.x += v1 * bf_lo(x1.y); a1.y += v1 * bf_hi(x1.y);
        a2.x += v1 * bf_lo(x1.z); a2.y += v1 * bf_hi(x1.z);
        a3.x += v1 * bf_lo(x1.w); a3.y += v1 * bf_hi(x1.w);
        a0.x += v2 * bf_lo(x2.x); a0.y += v2 * bf_hi(x2.x);
        a1.x += v2 * bf_lo(x2.y); a1.y += v2 * bf_hi(x2.y);
        a2.x += v2 * bf_lo(x2.z); a2.y += v2 * bf_hi(x2.z);
        a3.x += v2 * bf_lo(x2.w); a3.y += v2 * bf_hi(x2.w);
        a0.x += v3 * bf_lo(x3.x); a0.y += v3 * bf_hi(x3.x);
        a1.x += v3 * bf_lo(x3.y); a1.y += v3 * bf_hi(x3.y);
        a2.x += v3 * bf_lo(x3.z); a2.y += v3 * bf_hi(x3.z);
        a3.x += v3 * bf_lo(x3.w); a3.y += v3 * bf_hi(x3.w);
    }
    for (; j < end; ++j) {
        int2 p = pairs[j];
        uint4 x = d4[(size_t)(p.x & 0x1FFFF) * 8 + t];
        float v = __int_as_float(p.y);
        a0.x += v * bf_lo(x.x); a0.y += v * bf_hi(x.x);
        a1.x += v * bf_lo(x.y); a1.y += v * bf_hi(x.y);
        a2.x += v * bf_lo(x.z); a2.y += v * bf_hi(x.z);
        a3.x += v * bf_lo(x.w); a3.y += v * bf_hi(x.w);
    }
    if (row < M) {
        float4 o0 = make_float4(a0.x, a0.y, a1.x, a1.y);
        float4 o1 = make_float4(a2.x, a2.y, a3.x, a3.y);
        float4* op = reinterpret_cast<float4*>(out + (size_t)row * 64 + t * 8);
        op[0] = o0;
        op[1] = o1;
    }
}

extern "C" void kernel_launch(void* const* d_in, const int* in_sizes, int n_in,
                              void* d_out, int out_size, void* d_ws, size_t ws_size,
                              hipStream_t stream) {
    const float* x  = (const float*)d_in[0];
    const float* W1 = (const float*)d_in[1];
    const float* W2 = (const float*)d_in[2];
    const float* ev = (const float*)d_in[3];
    const int*   es = (const int*)d_in[4];
    const int*   ed = (const int*)d_in[5];
    float* out = (float*)d_out;

    const int M = in_sizes[0] / NFEAT;   // 100000
    const int E = in_sizes[3];           // 1.6M
    const int nbuk = (M + 255) >> 8;     // 391

    size_t off = 0;
    auto alloc = [&](size_t bytes) -> void* {
        void* p = (char*)d_ws + off;
        off += (bytes + 255) & ~(size_t)255;
        return p;
    };
    unsigned short* sup_bf  = (unsigned short*)alloc((size_t)M * NHID * 2);
    unsigned short* sup2_bf = (unsigned short*)alloc((size_t)M * NCLASS * 2);
    unsigned short* W1T     = (unsigned short*)alloc((size_t)NHID * NFEAT * 2);
    unsigned short* W2T     = (unsigned short*)alloc((size_t)NCLASS * NHID * 2);
    int*  row_beg = (int*) alloc((size_t)M * sizeof(int));
    int*  row_end = (int*) alloc((size_t)M * sizeof(int));
    int*  bcur    = (int*) alloc(512 * sizeof(int));
    int2* tmp     = (int2*)alloc((size_t)nbuk * CAP * sizeof(int2));   // gapped
    int2* pairs   = (int2*)alloc((size_t)nbuk * CAP * sizeof(int2));   // gapped
    (void)ws_size;

    const int pgrid = (E + EPB - 1) / EPB;           // scatter blocks (196)
    const int castg = (NFEAT * NHID + 255) / 256;    // cast blocks (128)
    const int g1grid = (M + 63) / 64;                // gemm1 blocks (1563)

    // K1: W cast + bcur init
    init_cast_kernel<<<castg + 1, 256, 0, stream>>>(W1, W2, W1T, W2T, bcur, nbuk);

    // K2: scatter (first pgrid blocks, bump-alloc) overlapped with GEMM1
    gemm1_scatter_fused_kernel<<<pgrid + g1grid, 256, 0, stream>>>(
        x, W1T, sup_bf, M, ev, es, ed, bcur, tmp, E, pgrid);

    // K3: per-row CSR within buckets (gapped layout)
    bucket_fine_kernel<<<nbuk, 256, 0, stream>>>(bcur, tmp, row_beg, row_end, pairs, M);

    // K4: sup2 = relu(spmm(A, sup)) @ W2   (h never hits HBM)
    spmm_gemm2_fused_kernel<<<(M + 15) / 16, 256, 0, stream>>>(
        row_beg, row_end, pairs, sup_bf, W2T, sup2_bf, M);

    // K5: layer-2 aggregate -> f32 out
    spmm_gather64_kernel<<<(M + 31) / 32, 256, 0, stream>>>(
        row_beg, row_end, pairs, sup2_bf, out, M);
}

// Round 15
// 164.983 us; speedup vs baseline: 1.2117x; 1.0021x over previous
//
#include <hip/hip_runtime.h>

constexpr int NFEAT  = 256;
constexpr int NHID   = 128;
constexpr int NCLASS = 64;

typedef __attribute__((ext_vector_type(8))) short short8;   // 8 bf16 (4 VGPRs)
typedef __attribute__((ext_vector_type(4))) float floatx4;  // MFMA accumulator

__device__ __forceinline__ unsigned short f2bf(float x) {
    unsigned u = __float_as_uint(x);
    u += 0x7FFFu + ((u >> 16) & 1u);   // RNE
    return (unsigned short)(u >> 16);
}
__device__ __forceinline__ float bf_lo(unsigned int p) { return __uint_as_float(p << 16); }
__device__ __forceinline__ float bf_hi(unsigned int p) { return __uint_as_float(p & 0xFFFF0000u); }

constexpr int EPB = 8192;   // edges per scatter block
constexpr int CAP = 8192;   // fixed bucket capacity (mean ~4092 per bucket)

// ---------------- K1: W cast + bcur init (block 0) ----------------
__global__ __launch_bounds__(256) void init_cast_kernel(
    const float* __restrict__ W1, const float* __restrict__ W2,
    unsigned short* __restrict__ W1T, unsigned short* __restrict__ W2T,
    int* __restrict__ bcur, int nbuk)
{
    if (blockIdx.x == 0) {
        for (int b = threadIdx.x; b < nbuk; b += 256) bcur[b] = b * CAP;
        return;
    }
    int i = ((int)blockIdx.x - 1) * 256 + threadIdx.x;
    if (i < NFEAT * NHID) {         // 256x128
        int k = i >> 7, n = i & 127;
        W1T[n * NFEAT + k] = f2bf(W1[i]);
    }
    if (i < NHID * NCLASS) {        // 128x64
        int k = i >> 6, n = i & 63;
        W2T[n * NHID + k] = f2bf(W2[i]);
    }
}

// ---------------- K2: bucket_scatter (blocks < sgrid) + GEMM1 (rest) ----------------
// Bump-allocation scatter: bcur pre-initialized to b*CAP, gapped tmp layout.
// GEMM1 body = round-5 proven 63us structure.
__global__ __launch_bounds__(256) void gemm1_scatter_fused_kernel(
    const float* __restrict__ A,               // x [M][256] f32
    const unsigned short* __restrict__ BT,     // W1T [128][256] bf16
    unsigned short* __restrict__ C,            // sup [M][128] bf16
    int M,
    const float* __restrict__ vals, const int* __restrict__ src,
    const int* __restrict__ dst, int* __restrict__ bcur,
    int2* __restrict__ tmp, int E, int sgrid)
{
    constexpr int KTOT = NFEAT, BN = NHID;
    constexpr int NB  = BN / 16;
    constexpr int LDA = 72;
    __shared__ unsigned short smem[64 * LDA + BN * LDA];   // 27648 B >= 4KB scatter use

    if ((int)blockIdx.x < sgrid) {
        // ---- scatter body (bump allocation) ----
        int* cnt  = reinterpret_cast<int*>(smem);
        int* base = cnt + 512;
        for (int i = threadIdx.x; i < 512; i += 256) cnt[i] = 0;
        __syncthreads();
        int begin = blockIdx.x * EPB;
        int endi = begin + EPB; if (endi > E) endi = E;
        for (int i = begin + threadIdx.x; i < endi; i += 256)
            atomicAdd(&cnt[dst[i] >> 8], 1);
        __syncthreads();
        for (int b = threadIdx.x; b < 512; b += 256) {
            int c = cnt[b];
            base[b] = c ? atomicAdd(&bcur[b], c) : 0;
            cnt[b] = 0;
        }
        __syncthreads();
        for (int i = begin + threadIdx.x; i < endi; i += 256) {
            int d = dst[i];
            int b = d >> 8;
            int pos = base[b] + atomicAdd(&cnt[b], 1);
            tmp[pos] = make_int2(src[i] | ((d & 255) << 17), __float_as_int(vals[i]));
        }
        return;
    }

    // ---- GEMM1 body ----
    unsigned short* As = smem;
    unsigned short* Bs = smem + 64 * LDA;
    const int tid = threadIdx.x;
    const int w   = tid >> 6;
    const int l   = tid & 63;
    const int row0 = ((int)blockIdx.x - sgrid) * 64;

    floatx4 acc[NB];
    #pragma unroll
    for (int i = 0; i < NB; ++i) acc[i] = (floatx4){0.f, 0.f, 0.f, 0.f};

    for (int k0 = 0; k0 < KTOT; k0 += 64) {
        #pragma unroll
        for (int i = 0; i < 4; ++i) {
            int c = tid + 256 * i;
            int r = c >> 4, k4 = (c & 15) * 4;
            int row = row0 + r;
            float4 v = (row < M) ? *reinterpret_cast<const float4*>(A + (size_t)row * KTOT + k0 + k4)
                                 : make_float4(0.f, 0.f, 0.f, 0.f);
            ushort4 b;
            b.x = f2bf(v.x); b.y = f2bf(v.y); b.z = f2bf(v.z); b.w = f2bf(v.w);
            *reinterpret_cast<ushort4*>(&As[r * LDA + k4]) = b;
        }
        #pragma unroll
        for (int i = 0; i < BN * 8 / 256; ++i) {
            int c = tid + 256 * i;
            int n = c >> 3, k8 = (c & 7) * 8;
            uint4 v = *reinterpret_cast<const uint4*>(BT + (size_t)n * KTOT + k0 + k8);
            *reinterpret_cast<uint4*>(&Bs[n * LDA + k8]) = v;
        }
        __syncthreads();
        #pragma unroll
        for (int ks = 0; ks < 2; ++ks) {
            short8 a = *reinterpret_cast<const short8*>(&As[(16 * w + (l & 15)) * LDA + ks * 32 + (l >> 4) * 8]);
            #pragma unroll
            for (int nb = 0; nb < NB; ++nb) {
                short8 b = *reinterpret_cast<const short8*>(&Bs[(16 * nb + (l & 15)) * LDA + ks * 32 + (l >> 4) * 8]);
                acc[nb] = __builtin_amdgcn_mfma_f32_16x16x32_bf16(a, b, acc[nb], 0, 0, 0);
            }
        }
        __syncthreads();
    }
    const int cr = (l >> 4) * 4;
    const int cc = l & 15;
    #pragma unroll
    for (int nb = 0; nb < NB; ++nb) {
        #pragma unroll
        for (int r = 0; r < 4; ++r) {
            int row = row0 + 16 * w + cr + r;
            if (row < M) C[(size_t)row * BN + 16 * nb + cc] = f2bf(acc[nb][r]);
        }
    }
}

// ---------------- K3: per-row CSR within buckets (gapped layout) ----------------
__global__ __launch_bounds__(256) void bucket_fine_kernel(
    const int* __restrict__ bcur,              // final cursors: end of bucket b
    const int2* __restrict__ tmp,
    int* __restrict__ row_beg, int* __restrict__ row_end,
    int2* __restrict__ pairs, int M)
{
    __shared__ int cnt[256];
    __shared__ int excl[256];
    __shared__ int cur[256];
    const int b = blockIdx.x;
    const int beg = b * CAP, endi = bcur[b];
    const int t = threadIdx.x;
    cnt[t] = 0;
    __syncthreads();
    for (int j = beg + t; j < endi; j += 256)
        atomicAdd(&cnt[(tmp[j].x >> 17) & 255], 1);
    __syncthreads();
    int v = cnt[t];
    excl[t] = v;
    __syncthreads();
    for (int off = 1; off < 256; off <<= 1) {
        int u = (t >= off) ? excl[t - off] : 0;
        __syncthreads();
        excl[t] += u;
        __syncthreads();
    }
    int ex = excl[t] - v;
    excl[t] = ex;
    cur[t] = 0;
    int row = (b << 8) + t;
    if (row < M) { row_beg[row] = beg + ex; row_end[row] = beg + ex + v; }
    __syncthreads();
    for (int j = beg + t; j < endi; j += 256) {
        int2 p = tmp[j];
        int dl = (p.x >> 17) & 255;
        int pos = beg + excl[dl] + atomicAdd(&cur[dl], 1);
        pairs[pos] = p;
    }
}

// ---------------- K4: FUSED layer-1 gather + relu + GEMM2 ----------------
__global__ __launch_bounds__(256) void spmm_gemm2_fused_kernel(
    const int*  __restrict__ row_beg,
    const int*  __restrict__ row_end,
    const int2* __restrict__ pairs,
    const unsigned short* __restrict__ dense,   // sup_bf  [M][128]
    const unsigned short* __restrict__ W2T,     // [64][128] bf16 (L1-resident)
    unsigned short*       __restrict__ sup2,    // [M][64] bf16
    int M)
{
    __shared__ unsigned short hs[16 * 128];     // 4KB, swizzled: byte ^= (r&7)<<4
    const int wv = threadIdx.x >> 6, l = threadIdx.x & 63;
    const int g = l >> 4, t = l & 15;
    const int row = blockIdx.x * 16 + wv * 4 + g;
    int beg = 0, end = 0;
    if (row < M) { beg = row_beg[row]; end = row_end[row]; }
    const uint4* d4 = reinterpret_cast<const uint4*>(dense);
    float2 a0 = {0.f, 0.f}, a1 = {0.f, 0.f}, a2 = {0.f, 0.f}, a3 = {0.f, 0.f};
    int j = beg;
    for (; j + 4 <= end; j += 4) {
        int2 p0 = pairs[j], p1 = pairs[j + 1], p2 = pairs[j + 2], p3 = pairs[j + 3];
        uint4 x0 = d4[(size_t)(p0.x & 0x1FFFF) * 16 + t];
        uint4 x1 = d4[(size_t)(p1.x & 0x1FFFF) * 16 + t];
        uint4 x2 = d4[(size_t)(p2.x & 0x1FFFF) * 16 + t];
        uint4 x3 = d4[(size_t)(p3.x & 0x1FFFF) * 16 + t];
        float v0 = __int_as_float(p0.y), v1 = __int_as_float(p1.y);
        float v2 = __int_as_float(p2.y), v3 = __int_as_float(p3.y);
        a0.x += v0 * bf_lo(x0.x); a0.y += v0 * bf_hi(x0.x);
        a1.x += v0 * bf_lo(x0.y); a1.y += v0 * bf_hi(x0.y);
        a2.x += v0 * bf_lo(x0.z); a2.y += v0 * bf_hi(x0.z);
        a3.x += v0 * bf_lo(x0.w); a3.y += v0 * bf_hi(x0.w);
        a0.x += v1 * bf_lo(x1.x); a0.y += v1 * bf_hi(x1.x);
        a1.x += v1 * bf_lo(x1.y); a1.y += v1 * bf_hi(x1.y);
        a2.x += v1 * bf_lo(x1.z); a2.y += v1 * bf_hi(x1.z);
        a3.x += v1 * bf_lo(x1.w); a3.y += v1 * bf_hi(x1.w);
        a0.x += v2 * bf_lo(x2.x); a0.y += v2 * bf_hi(x2.x);
        a1.x += v2 * bf_lo(x2.y); a1.y += v2 * bf_hi(x2.y);
        a2.x += v2 * bf_lo(x2.z); a2.y += v2 * bf_hi(x2.z);
        a3.x += v2 * bf_lo(x2.w); a3.y += v2 * bf_hi(x2.w);
        a0.x += v3 * bf_lo(x3.x); a0.y += v3 * bf_hi(x3.x);
        a1.x += v3 * bf_lo(x3.y); a1.y += v3 * bf_hi(x3.y);
        a2.x += v3 * bf_lo(x3.z); a2.y += v3 * bf_hi(x3.z);
        a3.x += v3 * bf_lo(x3.w); a3.y += v3 * bf_hi(x3.w);
    }
    for (; j < end; ++j) {
        int2 p = pairs[j];
        uint4 x = d4[(size_t)(p.x & 0x1FFFF) * 16 + t];
        float v = __int_as_float(p.y);
        a0.x += v * bf_lo(x.x); a0.y += v * bf_hi(x.x);
        a1.x += v * bf_lo(x.y); a1.y += v * bf_hi(x.y);
        a2.x += v * bf_lo(x.z); a2.y += v * bf_hi(x.z);
        a3.x += v * bf_lo(x.w); a3.y += v * bf_hi(x.w);
    }
    {
        uint4 o;
        o.x = (unsigned)f2bf(fmaxf(a0.x, 0.f)) | ((unsigned)f2bf(fmaxf(a0.y, 0.f)) << 16);
        o.y = (unsigned)f2bf(fmaxf(a1.x, 0.f)) | ((unsigned)f2bf(fmaxf(a1.y, 0.f)) << 16);
        o.z = (unsigned)f2bf(fmaxf(a2.x, 0.f)) | ((unsigned)f2bf(fmaxf(a2.y, 0.f)) << 16);
        o.w = (unsigned)f2bf(fmaxf(a3.x, 0.f)) | ((unsigned)f2bf(fmaxf(a3.y, 0.f)) << 16);
        const int rloc = wv * 4 + g;
        const int byte = (t * 16) ^ ((rloc & 7) << 4);
        *reinterpret_cast<uint4*>(reinterpret_cast<char*>(hs) + rloc * 256 + byte) = o;
    }
    __syncthreads();
    floatx4 acc = (floatx4){0.f, 0.f, 0.f, 0.f};
    const int lr = l & 15, lk = l >> 4;
    #pragma unroll
    for (int ks = 0; ks < 4; ++ks) {
        const int byte = (ks * 64 + lk * 16) ^ ((lr & 7) << 4);
        short8 a = *reinterpret_cast<const short8*>(reinterpret_cast<const char*>(hs) + lr * 256 + byte);
        short8 b = *reinterpret_cast<const short8*>(W2T + (size_t)(wv * 16 + lr) * NHID + ks * 32 + lk * 8);
        acc = __builtin_amdgcn_mfma_f32_16x16x32_bf16(a, b, acc, 0, 0, 0);
    }
    const int cr = lk * 4, cc = lr;
    #pragma unroll
    for (int q = 0; q < 4; ++q) {
        int orow = blockIdx.x * 16 + cr + q;
        if (orow < M) sup2[(size_t)orow * NCLASS + wv * 16 + cc] = f2bf(acc[q]);
    }
}

// ---------------- K5: layer-2 gather, D=64, 8-lane group per dst row, f32 out ----------------
__global__ __launch_bounds__(256) void spmm_gather64_kernel(
    const int*  __restrict__ row_beg,
    const int*  __restrict__ row_end,
    const int2* __restrict__ pairs,
    const unsigned short* __restrict__ dense,   // bf16 [M][64]
    float*                __restrict__ out,     // f32 [M][64]
    int M)
{
    const int wv = threadIdx.x >> 6, l = threadIdx.x & 63;
    const int g = l >> 3, t = l & 7;
    const int row = blockIdx.x * 32 + wv * 8 + g;
    int beg = 0, end = 0;
    if (row < M) { beg = row_beg[row]; end = row_end[row]; }
    const uint4* d4 = reinterpret_cast<const uint4*>(dense);
    float2 a0 = {0.f, 0.f}, a1 = {0.f, 0.f}, a2 = {0.f, 0.f}, a3 = {0.f, 0.f};
    int j = beg;
    for (; j + 4 <= end; j += 4) {
        int2 p0 = pairs[j], p1 = pairs[j + 1], p2 = pairs[j + 2], p3 = pairs[j + 3];
        uint4 x0 = d4[(size_t)(p0.x & 0x1FFFF) * 8 + t];
        uint4 x1 = d4[(size_t)(p1.x & 0x1FFFF) * 8 + t];
        uint4 x2 = d4[(size_t)(p2.x & 0x1FFFF) * 8 + t];
        uint4 x3 = d4[(size_t)(p3.x & 0x1FFFF) * 8 + t];
        float v0 = __int_as_float(p0.y), v1 = __int_as_float(p1.y);
        float v2 = __int_as_float(p2.y), v3 = __int_as_float(p3.y);
        a0.x += v0 * bf_lo(x0.x); a0.y += v0 * bf_hi(x0.x);
        a1.x += v0 * bf_lo(x0.y); a1.y += v0 * bf_hi(x0.y);
        a2.x += v0 * bf_lo(x0.z); a2.y += v0 * bf_hi(x0.z);
        a3.x += v0 * bf_lo(x0.w); a3.y += v0 * bf_hi(x0.w);
        a0.x += v1 * bf_lo(x1.x); a0.y += v1 * bf_hi(x1.x);
        a1.x += v1 * bf_lo(x1.y); a1.y += v1 * bf_hi(x1.y);
        a2.x += v1 * bf_lo(x1.z); a2.y += v1 * bf_hi(x1.z);
        a3.x += v1 * bf_lo(x1.w); a3.y += v1 * bf_hi(x1.w);
        a0.x += v2 * bf_lo(x2.x); a0.y += v2 * bf_hi(x2.x);
        a1.x += v2 * bf_lo(x2.y); a1.y += v2 * bf_hi(x2.y);
        a2.x += v2 * bf_lo(x2.z); a2.y += v2 * bf_hi(x2.z);
        a3.x += v2 * bf_lo(x2.w); a3.y += v2 * bf_hi(x2.w);
        a0.x += v3 * bf_lo(x3.x); a0.y += v3 * bf_hi(x3.x);
        a1.x += v3 * bf_lo(x3.y); a1.y += v3 * bf_hi(x3.y);
        a2.x += v3 * bf_lo(x3.z); a2.y += v3 * bf_hi(x3.z);
        a3.x += v3 * bf_lo(x3.w); a3.y += v3 * bf_hi(x3.w);
    }
    for (; j < end; ++j) {
        int2 p = pairs[j];
        uint4 x = d4[(size_t)(p.x & 0x1FFFF) * 8 + t];
        float v = __int_as_float(p.y);
        a0.x += v * bf_lo(x.x); a0.y += v * bf_hi(x.x);
        a1.x += v * bf_lo(x.y); a1.y += v * bf_hi(x.y);
        a2.x += v * bf_lo(x.z); a2.y += v * bf_hi(x.z);
        a3.x += v * bf_lo(x.w); a3.y += v * bf_hi(x.w);
    }
    if (row < M) {
        float4 o0 = make_float4(a0.x, a0.y, a1.x, a1.y);
        float4 o1 = make_float4(a2.x, a2.y, a3.x, a3.y);
        float4* op = reinterpret_cast<float4*>(out + (size_t)row * 64 + t * 8);
        op[0] = o0;
        op[1] = o1;
    }
}

extern "C" void kernel_launch(void* const* d_in, const int* in_sizes, int n_in,
                              void* d_out, int out_size, void* d_ws, size_t ws_size,
                              hipStream_t stream) {
    const float* x  = (const float*)d_in[0];
    const float* W1 = (const float*)d_in[1];
    const float* W2 = (const float*)d_in[2];
    const float* ev = (const float*)d_in[3];
    const int*   es = (const int*)d_in[4];
    const int*   ed = (const int*)d_in[5];
    float* out = (float*)d_out;

    const int M = in_sizes[0] / NFEAT;   // 100000
    const int E = in_sizes[3];           // 1.6M
    const int nbuk = (M + 255) >> 8;     // 391

    size_t off = 0;
    auto alloc = [&](size_t bytes) -> void* {
        void* p = (char*)d_ws + off;
        off += (bytes + 255) & ~(size_t)255;
        return p;
    };
    unsigned short* sup_bf  = (unsigned short*)alloc((size_t)M * NHID * 2);
    unsigned short* sup2_bf = (unsigned short*)alloc((size_t)M * NCLASS * 2);
    unsigned short* W1T     = (unsigned short*)alloc((size_t)NHID * NFEAT * 2);
    unsigned short* W2T     = (unsigned short*)alloc((size_t)NCLASS * NHID * 2);
    int*  row_beg = (int*) alloc((size_t)M * sizeof(int));
    int*  row_end = (int*) alloc((size_t)M * sizeof(int));
    int*  bcur    = (int*) alloc(512 * sizeof(int));
    int2* tmp     = (int2*)alloc((size_t)nbuk * CAP * sizeof(int2));   // gapped
    int2* pairs   = (int2*)alloc((size_t)nbuk * CAP * sizeof(int2));   // gapped
    (void)ws_size;

    const int pgrid = (E + EPB - 1) / EPB;           // scatter blocks (196)
    const int castg = (NFEAT * NHID + 255) / 256;    // cast blocks (128)
    const int g1grid = (M + 63) / 64;                // gemm1 blocks (1563)

    // K1: W cast + bcur init (no count, no scan, no memset)
    init_cast_kernel<<<castg + 1, 256, 0, stream>>>(W1, W2, W1T, W2T, bcur, nbuk);

    // K2: scatter (first pgrid blocks, bump-alloc) overlapped with GEMM1
    gemm1_scatter_fused_kernel<<<pgrid + g1grid, 256, 0, stream>>>(
        x, W1T, sup_bf, M, ev, es, ed, bcur, tmp, E, pgrid);

    // K3: per-row CSR within buckets (gapped layout)
    bucket_fine_kernel<<<nbuk, 256, 0, stream>>>(bcur, tmp, row_beg, row_end, pairs, M);

    // K4: sup2 = relu(spmm(A, sup)) @ W2   (h never hits HBM)
    spmm_gemm2_fused_kernel<<<(M + 15) / 16, 256, 0, stream>>>(
        row_beg, row_end, pairs, sup_bf, W2T, sup2_bf, M);

    // K5: layer-2 aggregate -> f32 out
    spmm_gather64_kernel<<<(M + 31) / 32, 256, 0, stream>>>(
        row_beg, row_end, pairs, sup2_bf, out, M);
}